// Round 3
// baseline (155.881 us; speedup 1.0000x reference)
//
#include <hip/hip_runtime.h>

// YOLO loss: N=8192, S=14, B=2, C=20. ncells = N*S*S = 1,605,632.
// d_in[0] pred (ncells*30 f32), d_in[1] tbox (ncells*4 f32),
// d_in[2] tcls (ncells*20 f32), d_in[3] mask (ncells, dtype detected at runtime)
// d_out: 5 f32 = [total, reg, contain, noobj, cls] / N
//
// R3: no contended atomics (per-block partials + reduce kernel),
//     4 tiles/block with register-prefetch software pipeline.

#define L_COORD 5.0f
#define L_NOOBJ 0.5f
#define TILE 256
#define NSTG 8   // float4 staging slots per thread (256 thr * 8 = 2048 >= 1920)

// ws layout: int flag at byte 512; float4 partials[nblocks] at byte 1024.

__global__ void detect_mask_kernel(const unsigned int* __restrict__ w, int nwords,
                                   int* __restrict__ flag) {
    __shared__ int s_int, s_flt;
    if (threadIdx.x == 0) { s_int = 1; s_flt = 1; }
    __syncthreads();
    int okInt = 1, okFlt = 1;
    for (int i = threadIdx.x; i < nwords; i += blockDim.x) {
        unsigned int v = w[i];
        okInt = okInt && (v == 0u || v == 1u);
        okFlt = okFlt && (v == 0u || v == 0x3F800000u);
    }
    if (!okInt) atomicAnd(&s_int, 0);
    if (!okFlt) atomicAnd(&s_flt, 0);
    __syncthreads();
    if (threadIdx.x == 0) *flag = s_int ? 1 : (s_flt ? 2 : 0);
}

__device__ __forceinline__ void prefetch_tile(const float4* __restrict__ gp4,
                                              long long total4, long long t,
                                              unsigned tid, float4* r) {
    long long b4 = t * (TILE * 30 / 4);
    #pragma unroll
    for (int i = 0; i < NSTG; ++i) {
        long long idx = b4 + tid + (i << 8);
        int lidx = tid + (i << 8);
        if (lidx < (TILE * 30 / 4) && idx < total4) r[i] = gp4[idx];
    }
}

__launch_bounds__(256)
__global__ void yolo_loss_kernel(const float* __restrict__ pred,
                                 const float* __restrict__ tbox,
                                 const float* __restrict__ tcls,
                                 const void* __restrict__ mask,
                                 const int* __restrict__ flag_p,
                                 float4* __restrict__ partials,
                                 int ncells, int ntiles) {
    __shared__ float sp[TILE * 30];           // 30720 B
    __shared__ float red[4][4];

    const int flg = *flag_p;                  // uniform
    const float invS = 1.0f / 14.0f;
    const unsigned tid = threadIdx.x;
    const float4* gp4 = (const float4*)pred;
    const long long total4 = ((long long)ncells * 30) >> 2;

    float a_reg = 0.f, a_con = 0.f, a_noo = 0.f, a_cls = 0.f;
    float4 r[NSTG];

    long long t = blockIdx.x;
    if (t < ntiles) prefetch_tile(gp4, total4, t, tid, r);

    for (; t < ntiles; t += gridDim.x) {
        __syncthreads();                      // LDS free from previous compute
        #pragma unroll
        for (int i = 0; i < NSTG; ++i) {
            int lidx = tid + (i << 8);
            if (lidx < (TILE * 30 / 4)) ((float4*)sp)[lidx] = r[i];
        }
        long long tn = t + gridDim.x;
        if (tn < ntiles) prefetch_tile(gp4, total4, tn, tid, r);
        __syncthreads();                      // staged data visible

        const long long c = t * TILE + tid;
        if (c < ncells) {
            float f;
            if (flg == 1)      f = (((const int*)mask)[c] != 0) ? 1.0f : 0.0f;
            else if (flg == 2) f = ((const float*)mask)[c];
            else               f = (((const unsigned char*)mask)[c] != 0) ? 1.0f : 0.0f;

            const float* my = sp + tid * 30;
            float px0 = my[0], py0 = my[1], pw0 = my[2], ph0 = my[3], cf0 = my[4];
            float px1 = my[5], py1 = my[6], pw1 = my[7], ph1 = my[8], cf1 = my[9];

            a_noo += (1.0f - f) * (cf0 * cf0 + cf1 * cf1);

            if (f != 0.0f) {
                const float4* tc4 = (const float4*)(tcls + (size_t)c * 20);
                float cl = 0.f;
                #pragma unroll
                for (int i = 0; i < 5; ++i) {
                    float4 tv = tc4[i];
                    float d0 = my[10 + 4 * i + 0] - tv.x;
                    float d1 = my[10 + 4 * i + 1] - tv.y;
                    float d2 = my[10 + 4 * i + 2] - tv.z;
                    float d3 = my[10 + 4 * i + 3] - tv.w;
                    cl += d0 * d0 + d1 * d1 + d2 * d2 + d3 * d3;
                }
                a_cls += f * cl;

                float4 tb = ((const float4*)tbox)[c];
                float tx1 = tb.x * invS - 0.5f * tb.z;
                float ty1 = tb.y * invS - 0.5f * tb.w;
                float tx2 = tb.x * invS + 0.5f * tb.z;
                float ty2 = tb.y * invS + 0.5f * tb.w;
                float ta  = (tx2 - tx1) * (ty2 - ty1);

                float x1 = px0 * invS - 0.5f * pw0, y1 = py0 * invS - 0.5f * ph0;
                float x2 = px0 * invS + 0.5f * pw0, y2 = py0 * invS + 0.5f * ph0;
                float lx = fmaxf(x1, tx1), ly = fmaxf(y1, ty1);
                float rx = fminf(x2, tx2), ry = fminf(y2, ty2);
                float wx = fmaxf(rx - lx, 0.f), wy = fmaxf(ry - ly, 0.f);
                float inter = wx * wy;
                float pa = (x2 - x1) * (y2 - y1);
                float iou0 = inter / (pa + ta - inter);

                x1 = px1 * invS - 0.5f * pw1; y1 = py1 * invS - 0.5f * ph1;
                x2 = px1 * invS + 0.5f * pw1; y2 = py1 * invS + 0.5f * ph1;
                lx = fmaxf(x1, tx1); ly = fmaxf(y1, ty1);
                rx = fminf(x2, tx2); ry = fminf(y2, ty2);
                wx = fmaxf(rx - lx, 0.f); wy = fmaxf(ry - ly, 0.f);
                inter = wx * wy;
                pa = (x2 - x1) * (y2 - y1);
                float iou1 = inter / (pa + ta - inter);

                int best = (iou1 > iou0) ? 1 : 0;   // first index wins ties
                float miou = fmaxf(iou0, iou1);

                float bx = best ? px1 : px0, by = best ? py1 : py0;
                float bw = best ? pw1 : pw0, bh = best ? ph1 : ph0;
                float bc = best ? cf1 : cf0;

                float dx = bx - tb.x, dy = by - tb.y;
                float sw = sqrtf(fmaxf(bw, 0.f)) - sqrtf(fmaxf(tb.z, 0.f));
                float sh = sqrtf(fmaxf(bh, 0.f)) - sqrtf(fmaxf(tb.w, 0.f));
                a_reg += f * (dx * dx + dy * dy + sw * sw + sh * sh);
                float dc = bc - miou;
                a_con += f * dc * dc;
            }
        }
    }

    // wave reduce, block reduce, single partial write (no atomics)
    #pragma unroll
    for (int off = 32; off > 0; off >>= 1) {
        a_reg += __shfl_down(a_reg, off, 64);
        a_con += __shfl_down(a_con, off, 64);
        a_noo += __shfl_down(a_noo, off, 64);
        a_cls += __shfl_down(a_cls, off, 64);
    }
    const int wid = threadIdx.x >> 6, lane = threadIdx.x & 63;
    if (lane == 0) {
        red[wid][0] = a_reg; red[wid][1] = a_con;
        red[wid][2] = a_noo; red[wid][3] = a_cls;
    }
    __syncthreads();
    if (threadIdx.x == 0) {
        float rg = 0.f, co = 0.f, no = 0.f, cl = 0.f;
        #pragma unroll
        for (int w = 0; w < 4; ++w) {
            rg += red[w][0]; co += red[w][1]; no += red[w][2]; cl += red[w][3];
        }
        partials[blockIdx.x] = make_float4(rg, co, no, cl);
    }
}

__launch_bounds__(256)
__global__ void reduce_kernel(const float4* __restrict__ partials, int nblocks,
                              float* __restrict__ out, float inv_n) {
    __shared__ float red[4][4];
    float rg = 0.f, co = 0.f, no = 0.f, cl = 0.f;
    for (int i = threadIdx.x; i < nblocks; i += blockDim.x) {
        float4 p = partials[i];
        rg += p.x; co += p.y; no += p.z; cl += p.w;
    }
    #pragma unroll
    for (int off = 32; off > 0; off >>= 1) {
        rg += __shfl_down(rg, off, 64);
        co += __shfl_down(co, off, 64);
        no += __shfl_down(no, off, 64);
        cl += __shfl_down(cl, off, 64);
    }
    const int wid = threadIdx.x >> 6, lane = threadIdx.x & 63;
    if (lane == 0) { red[wid][0] = rg; red[wid][1] = co; red[wid][2] = no; red[wid][3] = cl; }
    __syncthreads();
    if (threadIdx.x == 0) {
        float r = 0.f, c2 = 0.f, n2 = 0.f, c3 = 0.f;
        #pragma unroll
        for (int w = 0; w < 4; ++w) { r += red[w][0]; c2 += red[w][1]; n2 += red[w][2]; c3 += red[w][3]; }
        float total = c3 + L_NOOBJ * n2 + L_COORD * r + c2;
        out[0] = total * inv_n;
        out[1] = r  * inv_n;
        out[2] = c2 * inv_n;
        out[3] = n2 * inv_n;
        out[4] = c3 * inv_n;
    }
}

extern "C" void kernel_launch(void* const* d_in, const int* in_sizes, int n_in,
                              void* d_out, int out_size, void* d_ws, size_t ws_size,
                              hipStream_t stream) {
    const float* pred = (const float*)d_in[0];
    const float* tbox = (const float*)d_in[1];
    const float* tcls = (const float*)d_in[2];
    const void*  mask = d_in[3];
    const int ncells = in_sizes[3];            // N*S*S
    const int N = ncells / (14 * 14);
    const int ntiles = (ncells + TILE - 1) / TILE;   // 6272

    int*    flag     = (int*)((char*)d_ws + 512);
    float4* partials = (float4*)((char*)d_ws + 1024);

    int nblocks = 1568;                        // 4 tiles/block
    if (nblocks > ntiles) nblocks = ntiles;
    long long maxb = ((long long)ws_size - 1024) / 16;
    if ((long long)nblocks > maxb) nblocks = (int)maxb;

    int nwords = ((ncells < 65536) ? ncells : 65536) / 4;
    detect_mask_kernel<<<1, 256, 0, stream>>>((const unsigned int*)mask, nwords, flag);

    yolo_loss_kernel<<<nblocks, 256, 0, stream>>>(pred, tbox, tcls, mask, flag,
                                                  partials, ncells, ntiles);

    reduce_kernel<<<1, 256, 0, stream>>>(partials, nblocks, (float*)d_out, 1.0f / (float)N);
}

// Round 4
// 58.386 us; speedup vs baseline: 2.6698x; 2.6698x over previous
//
#include <hip/hip_runtime.h>

// YOLO loss: N=8192, S=14, B=2, C=20. ncells = N*S*S = 1,605,632.
// d_in[0] pred (ncells*30 f32), d_in[1] tbox (ncells*4 f32),
// d_in[2] tcls (ncells*20 f32), d_in[3] mask (ncells, dtype detected at runtime)
// d_out: 5 f32 = [total, reg, contain, noobj, cls] / N
//
// R4: EXACT R2 structure (1 tile/block, LDS stage, best measured 115us),
//     only change: block partials to d_ws + reduce kernel (no contended atomics).

#define L_COORD 5.0f
#define L_NOOBJ 0.5f
#define TILE 256

// ws layout: int flag at byte 512; float4 partials[ntiles] at byte 1024.

__global__ void detect_mask_kernel(const unsigned int* __restrict__ w, int nwords,
                                   int* __restrict__ flag) {
    __shared__ int s_int, s_flt;
    if (threadIdx.x == 0) { s_int = 1; s_flt = 1; }
    __syncthreads();
    int okInt = 1, okFlt = 1;
    for (int i = threadIdx.x; i < nwords; i += blockDim.x) {
        unsigned int v = w[i];
        okInt = okInt && (v == 0u || v == 1u);
        okFlt = okFlt && (v == 0u || v == 0x3F800000u);
    }
    if (!okInt) atomicAnd(&s_int, 0);
    if (!okFlt) atomicAnd(&s_flt, 0);
    __syncthreads();
    if (threadIdx.x == 0) *flag = s_int ? 1 : (s_flt ? 2 : 0);
}

__launch_bounds__(256)
__global__ void yolo_loss_kernel(const float* __restrict__ pred,
                                 const float* __restrict__ tbox,
                                 const float* __restrict__ tcls,
                                 const void* __restrict__ mask,
                                 const int* __restrict__ flag_p,
                                 float4* __restrict__ partials,
                                 int ncells) {
    __shared__ float sp[TILE * 30];           // 30720 B
    __shared__ float red[4][4];

    const int flg = *flag_p;                  // uniform
    const float invS = 1.0f / 14.0f;

    const int tile = blockIdx.x;
    const size_t base = (size_t)tile * TILE;
    int nvalid = ncells - (int)base;
    if (nvalid > TILE) nvalid = TILE;

    // ---- coalesced stage of pred tile into LDS ----
    if (nvalid == TILE) {
        const float4* gp = (const float4*)(pred + base * 30);
        float4* sp4 = (float4*)sp;
        #pragma unroll
        for (int i = 0; i < 8; ++i) {
            int idx = threadIdx.x + (i << 8);
            if (idx < (TILE * 30 / 4)) sp4[idx] = gp[idx];
        }
    } else {
        for (int i = threadIdx.x; i < nvalid * 30; i += blockDim.x)
            sp[i] = pred[base * 30 + i];
    }
    __syncthreads();

    float a_reg = 0.f, a_con = 0.f, a_noo = 0.f, a_cls = 0.f;

    if ((int)threadIdx.x < nvalid) {
        const int c = (int)base + threadIdx.x;
        float f;
        if (flg == 1)      f = (((const int*)mask)[c] != 0) ? 1.0f : 0.0f;
        else if (flg == 2) f = ((const float*)mask)[c];
        else               f = (((const unsigned char*)mask)[c] != 0) ? 1.0f : 0.0f;

        const float* my = sp + threadIdx.x * 30;
        float px0 = my[0], py0 = my[1], pw0 = my[2], ph0 = my[3], cf0 = my[4];
        float px1 = my[5], py1 = my[6], pw1 = my[7], ph1 = my[8], cf1 = my[9];

        a_noo = (1.0f - f) * (cf0 * cf0 + cf1 * cf1);

        if (f != 0.0f) {
            const float4* tc4 = (const float4*)(tcls + (size_t)c * 20);  // 80B/cell
            float cl = 0.f;
            #pragma unroll
            for (int i = 0; i < 5; ++i) {
                float4 t = tc4[i];
                float d0 = my[10 + 4 * i + 0] - t.x;
                float d1 = my[10 + 4 * i + 1] - t.y;
                float d2 = my[10 + 4 * i + 2] - t.z;
                float d3 = my[10 + 4 * i + 3] - t.w;
                cl += d0 * d0 + d1 * d1 + d2 * d2 + d3 * d3;
            }
            a_cls = f * cl;

            float4 tb = ((const float4*)tbox)[c];
            float tx1 = tb.x * invS - 0.5f * tb.z;
            float ty1 = tb.y * invS - 0.5f * tb.w;
            float tx2 = tb.x * invS + 0.5f * tb.z;
            float ty2 = tb.y * invS + 0.5f * tb.w;
            float ta  = (tx2 - tx1) * (ty2 - ty1);

            // IoU box 0
            float x1 = px0 * invS - 0.5f * pw0, y1 = py0 * invS - 0.5f * ph0;
            float x2 = px0 * invS + 0.5f * pw0, y2 = py0 * invS + 0.5f * ph0;
            float lx = fmaxf(x1, tx1), ly = fmaxf(y1, ty1);
            float rx = fminf(x2, tx2), ry = fminf(y2, ty2);
            float wx = fmaxf(rx - lx, 0.f), wy = fmaxf(ry - ly, 0.f);
            float inter = wx * wy;
            float pa = (x2 - x1) * (y2 - y1);
            float iou0 = inter / (pa + ta - inter);
            // IoU box 1
            x1 = px1 * invS - 0.5f * pw1; y1 = py1 * invS - 0.5f * ph1;
            x2 = px1 * invS + 0.5f * pw1; y2 = py1 * invS + 0.5f * ph1;
            lx = fmaxf(x1, tx1); ly = fmaxf(y1, ty1);
            rx = fminf(x2, tx2); ry = fminf(y2, ty2);
            wx = fmaxf(rx - lx, 0.f); wy = fmaxf(ry - ly, 0.f);
            inter = wx * wy;
            pa = (x2 - x1) * (y2 - y1);
            float iou1 = inter / (pa + ta - inter);

            // jnp.argmax: first index on tie -> box1 wins only if strictly greater
            int best = (iou1 > iou0) ? 1 : 0;
            float miou = fmaxf(iou0, iou1);

            float bx = best ? px1 : px0, by = best ? py1 : py0;
            float bw = best ? pw1 : pw0, bh = best ? ph1 : ph0;
            float bc = best ? cf1 : cf0;

            float dx = bx - tb.x, dy = by - tb.y;
            float sw = sqrtf(fmaxf(bw, 0.f)) - sqrtf(fmaxf(tb.z, 0.f));
            float sh = sqrtf(fmaxf(bh, 0.f)) - sqrtf(fmaxf(tb.w, 0.f));
            a_reg = f * (dx * dx + dy * dy + sw * sw + sh * sh);
            float dc = bc - miou;
            a_con = f * dc * dc;
        }
    }

    // ---- wave reduce, block reduce, ONE uncontended partial store ----
    #pragma unroll
    for (int off = 32; off > 0; off >>= 1) {
        a_reg += __shfl_down(a_reg, off, 64);
        a_con += __shfl_down(a_con, off, 64);
        a_noo += __shfl_down(a_noo, off, 64);
        a_cls += __shfl_down(a_cls, off, 64);
    }
    const int wid = threadIdx.x >> 6, lane = threadIdx.x & 63;
    if (lane == 0) {
        red[wid][0] = a_reg; red[wid][1] = a_con;
        red[wid][2] = a_noo; red[wid][3] = a_cls;
    }
    __syncthreads();
    if (threadIdx.x == 0) {
        float rg = 0.f, co = 0.f, no = 0.f, cl = 0.f;
        #pragma unroll
        for (int w = 0; w < 4; ++w) {
            rg += red[w][0]; co += red[w][1]; no += red[w][2]; cl += red[w][3];
        }
        partials[blockIdx.x] = make_float4(rg, co, no, cl);
    }
}

__launch_bounds__(256)
__global__ void reduce_kernel(const float4* __restrict__ partials, int nblocks,
                              float* __restrict__ out, float inv_n) {
    __shared__ float red[4][4];
    float rg = 0.f, co = 0.f, no = 0.f, cl = 0.f;
    for (int i = threadIdx.x; i < nblocks; i += blockDim.x) {
        float4 p = partials[i];
        rg += p.x; co += p.y; no += p.z; cl += p.w;
    }
    #pragma unroll
    for (int off = 32; off > 0; off >>= 1) {
        rg += __shfl_down(rg, off, 64);
        co += __shfl_down(co, off, 64);
        no += __shfl_down(no, off, 64);
        cl += __shfl_down(cl, off, 64);
    }
    const int wid = threadIdx.x >> 6, lane = threadIdx.x & 63;
    if (lane == 0) { red[wid][0] = rg; red[wid][1] = co; red[wid][2] = no; red[wid][3] = cl; }
    __syncthreads();
    if (threadIdx.x == 0) {
        float r = 0.f, c2 = 0.f, n2 = 0.f, c3 = 0.f;
        #pragma unroll
        for (int w = 0; w < 4; ++w) { r += red[w][0]; c2 += red[w][1]; n2 += red[w][2]; c3 += red[w][3]; }
        float total = c3 + L_NOOBJ * n2 + L_COORD * r + c2;
        out[0] = total * inv_n;
        out[1] = r  * inv_n;
        out[2] = c2 * inv_n;
        out[3] = n2 * inv_n;
        out[4] = c3 * inv_n;
    }
}

extern "C" void kernel_launch(void* const* d_in, const int* in_sizes, int n_in,
                              void* d_out, int out_size, void* d_ws, size_t ws_size,
                              hipStream_t stream) {
    const float* pred = (const float*)d_in[0];
    const float* tbox = (const float*)d_in[1];
    const float* tcls = (const float*)d_in[2];
    const void*  mask = d_in[3];
    const int ncells = in_sizes[3];            // N*S*S
    const int N = ncells / (14 * 14);
    const int ntiles = (ncells + TILE - 1) / TILE;   // 6272

    int*    flag     = (int*)((char*)d_ws + 512);
    float4* partials = (float4*)((char*)d_ws + 1024);

    // mask dtype probe: 16 KB sample is plenty to classify int32/f32/byte
    int nwords = ((ncells < 16384) ? ncells : 16384) / 4;
    detect_mask_kernel<<<1, 256, 0, stream>>>((const unsigned int*)mask, nwords, flag);

    yolo_loss_kernel<<<ntiles, 256, 0, stream>>>(pred, tbox, tcls, mask, flag,
                                                 partials, ncells);

    reduce_kernel<<<1, 256, 0, stream>>>(partials, ntiles, (float*)d_out, 1.0f / (float)N);
}